// Round 6
// baseline (351.581 us; speedup 1.0000x reference)
//
#include <hip/hip_runtime.h>

#define HDIM 1024
#define LSEQ 2048
#define NBATCH 4
#define NS 16
#define BL (NBATCH * LSEQ)   // 8192 rows
#define KDIM 1024
#define NX 1056              // 2*NS + HDIM
#define NXPAD 1152           // padded to 9*128
#define NCHUNK 64            // L chunks for the 3-phase scan
#define CLEN 32              // LSEQ / NCHUNK
#define KS 8                 // steps per LDS staging buffer

typedef unsigned short u16;
typedef short short8 __attribute__((ext_vector_type(8)));
typedef float f32x4 __attribute__((ext_vector_type(4)));
typedef u16 u16x8 __attribute__((ext_vector_type(8)));

__device__ __forceinline__ u16 f2bf(float f) {
  union { float f; unsigned u; } v; v.f = f;
  unsigned r = v.u + 0x7fffu + ((v.u >> 16) & 1u);   // round-to-nearest-even
  return (u16)(r >> 16);
}

// async global->LDS, 16B per lane (used by scan staging only)
__device__ __forceinline__ void ld16(const void* g, void* l) {
  __builtin_amdgcn_global_load_lds(
      (const __attribute__((address_space(1))) unsigned int*)g,
      (__attribute__((address_space(3))) unsigned int*)l, 16, 0, 0);
}

// ---------------- fused fp32 -> bf16 conversion (x, Wx->padded, Wout) ------
__global__ __launch_bounds__(256) void cvt_all_kernel(const float* __restrict__ x,
                                                      const float* __restrict__ Wx,
                                                      const float* __restrict__ Wout,
                                                      u16* __restrict__ x_bf,
                                                      u16* __restrict__ wx_bf,
                                                      u16* __restrict__ wo_bf) {
  const int blk = blockIdx.x;
  const float* in;
  u16* out;
  int i;
  bool zero = false;
  if (blk < 4096) {
    i = (blk * 256 + threadIdx.x) * 8;
    in = x; out = x_bf;
  } else if (blk < 4672) {
    i = ((blk - 4096) * 256 + threadIdx.x) * 8;
    in = Wx; out = wx_bf;
    zero = (i >> 10) >= NX;                 // pad rows 1056..1151
  } else {
    i = ((blk - 4672) * 256 + threadIdx.x) * 8;
    in = Wout; out = wo_bf;
  }
  u16x8 r;
  if (!zero) {
    float4 a = *(const float4*)(in + i);
    float4 b = *(const float4*)(in + i + 4);
    r[0] = f2bf(a.x); r[1] = f2bf(a.y); r[2] = f2bf(a.z); r[3] = f2bf(a.w);
    r[4] = f2bf(b.x); r[5] = f2bf(b.y); r[6] = f2bf(b.z); r[7] = f2bf(b.w);
  } else {
#pragma unroll
    for (int t = 0; t < 8; ++t) r[t] = 0;
  }
  *(u16x8*)(out + i) = r;
}

// ---------------- bf16 GEMM:  C(MxN) = A(MxK) * B(NxK)^T ----------------
// ROUND-6: wave-direct GEMM. One wave per block (64 thr), 64x64 tile,
// NO LDS, NO barriers. MFMA fragments load straight from global into VGPRs
// (A/B are L2-resident at this problem size: 16 MB / 2.3 MB — LDS staging
// buys no HBM savings, and its barrier forces a vmcnt(0) drain that r3-r5
// proved structural: MfmaUtil stuck ~8-10% with VALU/HBM/LDS all idle).
// Register double-buffer of the next K-step: compiler emits fine-grained
// s_waitcnt vmcnt(N) (pure VGPR deps, no LDS alias conservatism) — the
// AITER-style MFMA<->load interleave the barrier loop can't express.
// Frag pattern per load: 16 rows x 64 B contiguous = full-sector 1 KB/instr.
template <int EPI>
__global__ __launch_bounds__(64) void gemm_wave(const u16* __restrict__ A,
                                                const u16* __restrict__ B,
                                                float* __restrict__ C,
                                                float* __restrict__ Bmo,
                                                float* __restrict__ Cmo,
                                                float* __restrict__ Dlo,
                                                int N) {
  const int lane = threadIdx.x;
  const int m0 = blockIdx.y * 64, n0 = blockIdx.x * 64;
  const int lr = lane & 15, lq = lane >> 4;
  f32x4 acc[4][4] = {};

  // lane's base pointers: row = tile_base + lr, k-phase = lq*8
  const u16* ap = A + (size_t)(m0 + lr) * KDIM + lq * 8;
  const u16* bp = B + (size_t)(n0 + lr) * KDIM + lq * 8;

  short8 a0[4], b0[4], a1[4], b1[4];
#define LDFRAG(da, db, koff)                                        \
  {                                                                 \
    _Pragma("unroll") for (int f = 0; f < 4; ++f) {                 \
      da[f] = *(const short8*)(ap + (size_t)f * 16 * KDIM + (koff));\
      db[f] = *(const short8*)(bp + (size_t)f * 16 * KDIM + (koff));\
    }                                                               \
  }
#define MFMA16(da, db)                                              \
  {                                                                 \
    _Pragma("unroll") for (int i = 0; i < 4; ++i)                   \
      _Pragma("unroll") for (int j = 0; j < 4; ++j)                 \
        acc[i][j] = __builtin_amdgcn_mfma_f32_16x16x32_bf16(        \
            da[i], db[j], acc[i][j], 0, 0, 0);                      \
  }

  LDFRAG(a0, b0, 0);
  for (int kt = 0; kt < KDIM / 32; kt += 2) {
    LDFRAG(a1, b1, (kt + 1) * 32);
    MFMA16(a0, b0);
    if (kt + 2 < KDIM / 32) LDFRAG(a0, b0, (kt + 2) * 32);
    MFMA16(a1, b1);
  }
#undef LDFRAG
#undef MFMA16

#pragma unroll
  for (int i = 0; i < 4; ++i) {
    const int gr0 = m0 + i * 16 + lq * 4;
#pragma unroll
    for (int j = 0; j < 4; ++j) {
      const int gc = n0 + j * 16 + lr;
      if (EPI == 0) {
        float* p = C + (size_t)gr0 * N + gc;
#pragma unroll
        for (int r = 0; r < 4; ++r) p[(size_t)r * N] = acc[i][j][r];
      } else {
        const int nt = gc >> 4;  // 16-col tile index
        if (nt == 0) {
#pragma unroll
          for (int r = 0; r < 4; ++r) Bmo[(gr0 + r) * NS + lr] = acc[i][j][r];
        } else if (nt == 1) {
#pragma unroll
          for (int r = 0; r < 4; ++r) Cmo[(gr0 + r) * NS + lr] = acc[i][j][r];
        } else if (nt < 66) {  // cols 32..1055 -> delta 0..1023
#pragma unroll
          for (int r = 0; r < 4; ++r) {
            float v = acc[i][j][r];
            // fast softplus: hw v_exp_f32/v_log_f32
            float sp = fmaxf(v, 0.f) + __logf(1.f + __expf(-fabsf(v)));
            Dlo[(size_t)(gr0 + r) * HDIM + (gc - 2 * NS)] = sp;
          }
        }
      }
    }
  }
}

// ---------------- chunked selective scan, 3 phases ----------------
// Thread = (b,h), all 16 n-states in registers (ILP 16, no shuffles).
// PHASE 1: per-chunk local scan from 0 -> store h_end[b][c][n][h], dtsum[b][c][h].
// PHASE 3: rerun chunk from h_start (slot c-1 of hbuf), emit y (bf16).
template <int PHASE>
__global__ __launch_bounds__(256) void scan_phase(
    const float* __restrict__ dlt, const float* __restrict__ xin,
    const float* __restrict__ Bm, const float* __restrict__ Cm,
    const float* __restrict__ A_log, const float* __restrict__ Dvec,
    float* __restrict__ hbuf,      // [b][chunk][n][h]
    float* __restrict__ dts_out,   // [b][chunk][h]
    u16* __restrict__ yout) {
  __shared__ __align__(16) float sdt[2][KS][256];   // 16 KB
  __shared__ __align__(16) float sx [2][KS][256];   // 16 KB
  __shared__ __align__(16) float sbt[CLEN][16];     //  2 KB
  __shared__ __align__(16) float sct[CLEN][16];     //  2 KB
  const int tid = threadIdx.x, lane = tid & 63, w = tid >> 6;
  const int b = blockIdx.x >> 6, c = blockIdx.x & 63;
  const int h0 = blockIdx.y << 8, h = h0 + tid;
  const size_t l0 = (size_t)b * LSEQ + (size_t)c * CLEN;

  auto stage = [&](int ks, int pb_) {
#pragma unroll
    for (int j = 0; j < 4; ++j) {
      const int idx = w * 4 + j;            // 0..15
      const int s = idx & 7;
      const size_t row = l0 + ks * KS + s;
      if (idx < 8)
        ld16(dlt + row * HDIM + h0 + lane * 4, (void*)&sdt[pb_][s][0]);
      else
        ld16(xin + row * HDIM + h0 + lane * 4, (void*)&sx[pb_][s][0]);
    }
  };

  stage(0, 0);
  if (w == 0) {
#pragma unroll
    for (int i = 0; i < 2; ++i)
      ld16(Bm + l0 * NS + i * 256 + lane * 4, (void*)(&sbt[0][0] + i * 256));
  } else if (w == 1 && PHASE == 3) {
#pragma unroll
    for (int i = 0; i < 2; ++i)
      ld16(Cm + l0 * NS + i * 256 + lane * 4, (void*)(&sct[0][0] + i * 256));
  }

  float Ae[16], hs[16];
#pragma unroll
  for (int n = 0; n < 16; ++n) Ae[n] = -expf(A_log[n]) * 1.44269504088896f;
  if (PHASE == 3 && c > 0) {
    const float* hp = hbuf + ((size_t)b * NCHUNK + (c - 1)) * NS * HDIM + h;
#pragma unroll
    for (int n = 0; n < 16; ++n) hs[n] = hp[(size_t)n * HDIM];
  } else {
#pragma unroll
    for (int n = 0; n < 16; ++n) hs[n] = 0.f;
  }
  const float Dh = (PHASE == 3) ? Dvec[h] : 0.f;
  float dts = 0.f;
  int pb = 0;
  for (int ks = 0; ks < CLEN / KS; ++ks) {
    __syncthreads();                          // drains this buffer's loads
    if (ks + 1 < CLEN / KS) stage(ks + 1, pb ^ 1);
#pragma unroll
    for (int s = 0; s < KS; ++s) {
      const int l = ks * KS + s;
      const float dt = sdt[pb][s][tid];
      const float xt = sx[pb][s][tid];
      const float dxt = dt * xt;
      if (PHASE == 1) dts += dt;
      float y = Dh * xt;
      const f32x4* btp = (const f32x4*)&sbt[l][0];
      const f32x4* ctp = (const f32x4*)&sct[l][0];
#pragma unroll
      for (int q = 0; q < 4; ++q) {
        const f32x4 b4 = btp[q];               // broadcast read (same addr)
        f32x4 c4;
        if (PHASE == 3) c4 = ctp[q];
#pragma unroll
        for (int r = 0; r < 4; ++r) {
          const int n = q * 4 + r;
          const float dA = exp2f(dt * Ae[n]);
          hs[n] = fmaf(dA, hs[n], b4[r] * dxt);
          if (PHASE == 3) y = fmaf(hs[n], c4[r], y);
        }
      }
      if (PHASE == 3) yout[(l0 + l) * HDIM + h] = f2bf(y);
    }
    pb ^= 1;
  }
  if (PHASE == 1) {
    float* hp = hbuf + ((size_t)b * NCHUNK + c) * NS * HDIM + h;
#pragma unroll
    for (int n = 0; n < 16; ++n) hp[(size_t)n * HDIM] = hs[n];
    dts_out[((size_t)b * NCHUNK + c) * HDIM + h] = dts;
  }
}

// PHASE 2: sequential prefix over chunks, in place (slot-shifted).
__global__ __launch_bounds__(256) void scan_combine(
    float* __restrict__ hbuf, const float* __restrict__ dts,
    const float* __restrict__ A_log) {
  const int id = blockIdx.x * 256 + threadIdx.x;   // 65536 = B*NS*H
  const int h = id & (HDIM - 1);
  const int n = (id >> 10) & (NS - 1);
  const int b = id >> 14;
  const float Ae = -expf(A_log[n]) * 1.44269504088896f;
  const size_t hstride = (size_t)NS * HDIM;
  float* hp = hbuf + ((size_t)b * NCHUNK * NS + n) * HDIM + h;
  const float* dp = dts + (size_t)b * NCHUNK * HDIM + h;
  float hs = 0.f;
  float nh = hp[0];
  float nd = dp[0];
  for (int c = 1; c < NCHUNK; ++c) {
    const float curh = nh, curd = nd;
    if (c < NCHUNK - 1) {                    // prefetch slot c (consumed at c+1)
      nh = hp[(size_t)c * hstride];
      nd = dp[(size_t)c * HDIM];
    }
    hs = fmaf(exp2f(Ae * curd), hs, curh);
    hp[(size_t)(c - 1) * hstride] = hs;      // h_start[c] -> slot c-1
  }
}

// ---------------- launcher ----------------
extern "C" void kernel_launch(void* const* d_in, const int* in_sizes, int n_in,
                              void* d_out, int out_size, void* d_ws, size_t ws_size,
                              hipStream_t stream) {
  (void)in_sizes; (void)n_in; (void)out_size; (void)ws_size;
  const float* x     = (const float*)d_in[0];
  const float* Wx    = (const float*)d_in[1];
  const float* A_log = (const float*)d_in[2];
  const float* Dv    = (const float*)d_in[3];
  const float* Wout  = (const float*)d_in[4];
  float* out = (float*)d_out;

  char* ws = (char*)d_ws;
  u16*   x_bf  = (u16*)(ws);                       // 16,777,216 B
  u16*   wx_bf = (u16*)(ws + 16777216);            //  2,359,296 B (padded 1152x1024)
  u16*   wo_bf = (u16*)(ws + 19136512);            //  2,097,152 B
  float* dlt   = (float*)(ws + 21233664);          // 33,554,432 B
  float* Bm    = (float*)(ws + 54788096);          //    524,288 B
  float* Cm    = (float*)(ws + 55312384);          //    524,288 B
  u16*   y_bf  = (u16*)(ws + 55836672);            // 16,777,216 B -> end 72,613,888
  // aliases (regions dead after GEMM1):
  float* hbuf = (float*)x_bf;    // 16 MB needed: h_end/h_start [4][64][16][1024]
  float* dts  = (float*)wx_bf;   //  1 MB needed: dtsum [4][64][1024]

  cvt_all_kernel<<<5184, 256, 0, stream>>>(x, Wx, Wout, x_bf, wx_bf, wo_bf);

  dim3 g1(NXPAD / 64, BL / 64);  // 18 x 128 = 2304 one-wave blocks (9/CU)
  gemm_wave<1><<<g1, 64, 0, stream>>>(x_bf, wx_bf, nullptr, Bm, Cm, dlt, NXPAD);

  dim3 gs(NBATCH * NCHUNK, HDIM / 256);  // 256 x 4 blocks
  scan_phase<1><<<gs, 256, 0, stream>>>(dlt, x, Bm, Cm, A_log, Dv, hbuf, dts, nullptr);
  scan_combine<<<256, 256, 0, stream>>>(hbuf, dts, A_log);
  scan_phase<3><<<gs, 256, 0, stream>>>(dlt, x, Bm, Cm, A_log, Dv, hbuf, dts, y_bf);

  dim3 g3(HDIM / 64, BL / 64);   // 16 x 128 = 2048 one-wave blocks (8/CU)
  gemm_wave<0><<<g3, 64, 0, stream>>>(y_bf, wo_bf, out, nullptr, nullptr, nullptr, HDIM);
}

// Round 7
// 316.611 us; speedup vs baseline: 1.1104x; 1.1104x over previous
//
#include <hip/hip_runtime.h>

#define HDIM 1024
#define LSEQ 2048
#define NBATCH 4
#define NS 16
#define BL (NBATCH * LSEQ)   // 8192 rows
#define KDIM 1024
#define NX 1056              // 2*NS + HDIM
#define NXPAD 1152           // padded to 9*128
#define NCHUNK 64            // L chunks for the 3-phase scan
#define CLEN 32              // LSEQ / NCHUNK
#define KS 8                 // steps per LDS staging buffer

typedef unsigned short u16;
typedef short short8 __attribute__((ext_vector_type(8)));
typedef float f32x4 __attribute__((ext_vector_type(4)));
typedef u16 u16x8 __attribute__((ext_vector_type(8)));

__device__ __forceinline__ u16 f2bf(float f) {
  union { float f; unsigned u; } v; v.f = f;
  unsigned r = v.u + 0x7fffu + ((v.u >> 16) & 1u);   // round-to-nearest-even
  return (u16)(r >> 16);
}
__device__ __forceinline__ float bf2f(u16 b) {
  union { unsigned u; float f; } v; v.u = ((unsigned)b) << 16; return v.f;
}
__device__ __forceinline__ u16 f2h(float f) {          // fp32 -> fp16 (e5m10)
  union { _Float16 h; u16 u; } v; v.h = (_Float16)f; return v.u;
}
__device__ __forceinline__ float h2f(u16 h) {
  union { u16 u; _Float16 h; } v; v.u = h; return (float)v.h;
}

// async global->LDS, 16B per lane; LDS dest = wave-uniform base + lane*16
// (global address may be arbitrary per lane — m104/m108 constraint is LDS-side)
__device__ __forceinline__ void ld16(const void* g, void* l) {
  __builtin_amdgcn_global_load_lds(
      (const __attribute__((address_space(1))) unsigned int*)g,
      (__attribute__((address_space(3))) unsigned int*)l, 16, 0, 0);
}

// ---------------- fused fp32 -> bf16 conversion (x, Wx->padded, Wout) ------
__global__ __launch_bounds__(256) void cvt_all_kernel(const float* __restrict__ x,
                                                      const float* __restrict__ Wx,
                                                      const float* __restrict__ Wout,
                                                      u16* __restrict__ x_bf,
                                                      u16* __restrict__ wx_bf,
                                                      u16* __restrict__ wo_bf) {
  const int blk = blockIdx.x;
  const float* in;
  u16* out;
  int i;
  bool zero = false;
  if (blk < 4096) {
    i = (blk * 256 + threadIdx.x) * 8;
    in = x; out = x_bf;
  } else if (blk < 4672) {
    i = ((blk - 4096) * 256 + threadIdx.x) * 8;
    in = Wx; out = wx_bf;
    zero = (i >> 10) >= NX;                 // pad rows 1056..1151
  } else {
    i = ((blk - 4672) * 256 + threadIdx.x) * 8;
    in = Wout; out = wo_bf;
  }
  u16x8 r;
  if (!zero) {
    float4 a = *(const float4*)(in + i);
    float4 b = *(const float4*)(in + i + 4);
    r[0] = f2bf(a.x); r[1] = f2bf(a.y); r[2] = f2bf(a.z); r[3] = f2bf(a.w);
    r[4] = f2bf(b.x); r[5] = f2bf(b.y); r[6] = f2bf(b.z); r[7] = f2bf(b.w);
  } else {
#pragma unroll
    for (int t = 0; t < 8; ++t) r[t] = 0;
  }
  *(u16x8*)(out + i) = r;
}

// ---------------- bf16 GEMM:  C(MxN) = A(MxK) * B(NxK)^T ----------------
// ROUND-5 config (best measured: 68 µs): 64x128 tile, BK=64, 4 waves in N,
// 24 KB LDS, 2-barrier K-loop, hoisted staging addresses. Round-6's no-LDS
// variant regressed (FETCH 32->75 MB: LDS staging is the L2-traffic
// condenser). EPI=1 now writes delta as fp16 (halves scan-side bytes).
template <int EPI>
__global__ __launch_bounds__(256) void gemm_bt(const u16* __restrict__ A,
                                               const u16* __restrict__ B,
                                               float* __restrict__ C,
                                               float* __restrict__ Bmo,
                                               float* __restrict__ Cmo,
                                               u16* __restrict__ Dlo,
                                               int N) {
  __shared__ __align__(16) u16 S[24 * 512];   // 24 KB
  const int tid = threadIdx.x, lane = tid & 63, w = tid >> 6;
  const int m0 = blockIdx.x * 64, n0 = blockIdx.y * 128;
  const int lr = lane & 15, lq = lane >> 4;
  f32x4 acc[4][2] = {};

  // hoisted staging descriptors: 6 global pointers + 6 LDS bases per wave
  const u16* gp0; const u16* gp1; const u16* gp2;
  const u16* gp3; const u16* gp4; const u16* gp5;
  u16 *lp0, *lp1, *lp2, *lp3, *lp4, *lp5;
  {
    const u16* gp[6]; u16* lp[6];
#pragma unroll
    for (int c = 0; c < 6; ++c) {
      const int ca = w * 6 + c;                     // chunk id 0..23
      if (ca < 8) {                                 // A: 64 rows x 64 k
        const int arow = ((ca >> 1) << 4) + lr;
        const int acol = ((ca & 1) << 5) + (lq << 3);
        gp[c] = A + (size_t)(m0 + arow) * KDIM + acol;
      } else {                                      // B: 128 rows x 64 k
        const int cb = ca - 8;
        const int brow = ((cb >> 1) << 4) + lr;
        const int bcol = ((cb & 1) << 5) + (lq << 3);
        gp[c] = B + (size_t)(n0 + brow) * KDIM + bcol;
      }
      lp[c] = (u16*)(S + ca * 512);
    }
    gp0 = gp[0]; gp1 = gp[1]; gp2 = gp[2]; gp3 = gp[3]; gp4 = gp[4]; gp5 = gp[5];
    lp0 = lp[0]; lp1 = lp[1]; lp2 = lp[2]; lp3 = lp[3]; lp4 = lp[4]; lp5 = lp[5];
  }

  for (int kt = 0; kt < KDIM / 64; ++kt) {
    __syncthreads();
    ld16(gp0, lp0); ld16(gp1, lp1); ld16(gp2, lp2);
    ld16(gp3, lp3); ld16(gp4, lp4); ld16(gp5, lp5);
    gp0 += 64; gp1 += 64; gp2 += 64; gp3 += 64; gp4 += 64; gp5 += 64;
    __syncthreads();
#pragma unroll
    for (int kh = 0; kh < 2; ++kh) {
      short8 af[4], bfr[2];
#pragma unroll
      for (int f = 0; f < 4; ++f)
        af[f] = *(const short8*)(S + (f * 2 + kh) * 512 + lane * 8);
#pragma unroll
      for (int j = 0; j < 2; ++j)
        bfr[j] = *(const short8*)(S + (8 + (w * 2 + j) * 2 + kh) * 512 + lane * 8);
#pragma unroll
      for (int i = 0; i < 4; ++i)
#pragma unroll
        for (int j = 0; j < 2; ++j)
          acc[i][j] = __builtin_amdgcn_mfma_f32_16x16x32_bf16(af[i], bfr[j], acc[i][j], 0, 0, 0);
    }
  }

#pragma unroll
  for (int i = 0; i < 4; ++i) {
    const int gr0 = m0 + i * 16 + lq * 4;
#pragma unroll
    for (int j = 0; j < 2; ++j) {
      const int gc = n0 + w * 32 + j * 16 + lr;
      if (EPI == 0) {
        float* p = C + (size_t)gr0 * N + gc;
#pragma unroll
        for (int r = 0; r < 4; ++r) p[(size_t)r * N] = acc[i][j][r];
      } else {
        const int nt = gc >> 4;  // 16-col tile index
        if (nt == 0) {
#pragma unroll
          for (int r = 0; r < 4; ++r) Bmo[(gr0 + r) * NS + lr] = acc[i][j][r];
        } else if (nt == 1) {
#pragma unroll
          for (int r = 0; r < 4; ++r) Cmo[(gr0 + r) * NS + lr] = acc[i][j][r];
        } else if (nt < 66) {  // cols 32..1055 -> delta 0..1023, fp16
#pragma unroll
          for (int r = 0; r < 4; ++r) {
            float v = acc[i][j][r];
            // fast softplus: hw v_exp_f32/v_log_f32
            float sp = fmaxf(v, 0.f) + __logf(1.f + __expf(-fabsf(v)));
            Dlo[(size_t)(gr0 + r) * HDIM + (gc - 2 * NS)] = f2h(sp);
          }
        }
      }
    }
  }
}

// ---------------- chunked selective scan, 3 phases ----------------
// Thread = (b,h), all 16 n-states in registers. ROUND-7: delta read as fp16,
// x read as bf16 (x_bf) — halves scan-side traffic. One ld16 wave-instr now
// stages TWO rows (32 lanes x 8 u16 per row); per-lane global rows differ,
// LDS dest stays uniform+lane*16 (legal per m104/m108).
template <int PHASE>
__global__ __launch_bounds__(256) void scan_phase(
    const u16* __restrict__ dlth, const u16* __restrict__ xb,
    const float* __restrict__ Bm, const float* __restrict__ Cm,
    const float* __restrict__ A_log, const float* __restrict__ Dvec,
    float* __restrict__ hbuf,      // [b][chunk][n][h]
    float* __restrict__ dts_out,   // [b][chunk][h]
    u16* __restrict__ yout) {
  __shared__ __align__(16) u16 sdt[2][KS][256];     // 8 KB (fp16)
  __shared__ __align__(16) u16 sx [2][KS][256];     // 8 KB (bf16)
  __shared__ __align__(16) float sbt[CLEN][16];     // 2 KB
  __shared__ __align__(16) float sct[CLEN][16];     // 2 KB
  const int tid = threadIdx.x, lane = tid & 63, w = tid >> 6;
  const int b = blockIdx.x >> 6, c = blockIdx.x & 63;
  const int h0 = blockIdx.y << 8, h = h0 + tid;
  const size_t l0 = (size_t)b * LSEQ + (size_t)c * CLEN;

  // staging: w0 -> dt (4 ld16, 2 rows each), w1 -> x, w2/w3 -> Bm/Cm (once)
  const int lrow = lane >> 5;            // 0/1: which of the 2 rows
  const int lcol = (lane & 31) << 3;     // h-offset within row (8 u16)
  auto stage = [&](int ks, int pb_) {
    if (w == 0) {
#pragma unroll
      for (int j = 0; j < 4; ++j) {
        const size_t row = l0 + ks * KS + j * 2 + lrow;
        ld16(dlth + row * HDIM + h0 + lcol, (void*)&sdt[pb_][j * 2][0]);
      }
    } else if (w == 1) {
#pragma unroll
      for (int j = 0; j < 4; ++j) {
        const size_t row = l0 + ks * KS + j * 2 + lrow;
        ld16(xb + row * HDIM + h0 + lcol, (void*)&sx[pb_][j * 2][0]);
      }
    }
  };

  stage(0, 0);
  if (w == 2) {
#pragma unroll
    for (int i = 0; i < 2; ++i)
      ld16(Bm + l0 * NS + i * 256 + lane * 4, (void*)(&sbt[0][0] + i * 256));
  } else if (w == 3 && PHASE == 3) {
#pragma unroll
    for (int i = 0; i < 2; ++i)
      ld16(Cm + l0 * NS + i * 256 + lane * 4, (void*)(&sct[0][0] + i * 256));
  }

  float Ae[16], hs[16];
#pragma unroll
  for (int n = 0; n < 16; ++n) Ae[n] = -expf(A_log[n]) * 1.44269504088896f;
  if (PHASE == 3 && c > 0) {
    const float* hp = hbuf + ((size_t)b * NCHUNK + (c - 1)) * NS * HDIM + h;
#pragma unroll
    for (int n = 0; n < 16; ++n) hs[n] = hp[(size_t)n * HDIM];
  } else {
#pragma unroll
    for (int n = 0; n < 16; ++n) hs[n] = 0.f;
  }
  const float Dh = (PHASE == 3) ? Dvec[h] : 0.f;
  float dts = 0.f;
  int pb = 0;
  for (int ks = 0; ks < CLEN / KS; ++ks) {
    __syncthreads();                          // drains this buffer's loads
    if (ks + 1 < CLEN / KS) stage(ks + 1, pb ^ 1);
#pragma unroll
    for (int s = 0; s < KS; ++s) {
      const int l = ks * KS + s;
      const float dt = h2f(sdt[pb][s][tid]);
      const float xt = bf2f(sx[pb][s][tid]);
      const float dxt = dt * xt;
      if (PHASE == 1) dts += dt;
      float y = Dh * xt;
      const f32x4* btp = (const f32x4*)&sbt[l][0];
      const f32x4* ctp = (const f32x4*)&sct[l][0];
#pragma unroll
      for (int q = 0; q < 4; ++q) {
        const f32x4 b4 = btp[q];               // broadcast read (same addr)
        f32x4 c4;
        if (PHASE == 3) c4 = ctp[q];
#pragma unroll
        for (int r = 0; r < 4; ++r) {
          const int n = q * 4 + r;
          const float dA = exp2f(dt * Ae[n]);
          hs[n] = fmaf(dA, hs[n], b4[r] * dxt);
          if (PHASE == 3) y = fmaf(hs[n], c4[r], y);
        }
      }
      if (PHASE == 3) yout[(l0 + l) * HDIM + h] = f2bf(y);
    }
    pb ^= 1;
  }
  if (PHASE == 1) {
    float* hp = hbuf + ((size_t)b * NCHUNK + c) * NS * HDIM + h;
#pragma unroll
    for (int n = 0; n < 16; ++n) hp[(size_t)n * HDIM] = hs[n];
    dts_out[((size_t)b * NCHUNK + c) * HDIM + h] = dts;
  }
}

// PHASE 2: sequential prefix over chunks, in place (slot-shifted).
__global__ __launch_bounds__(256) void scan_combine(
    float* __restrict__ hbuf, const float* __restrict__ dts,
    const float* __restrict__ A_log) {
  const int id = blockIdx.x * 256 + threadIdx.x;   // 65536 = B*NS*H
  const int h = id & (HDIM - 1);
  const int n = (id >> 10) & (NS - 1);
  const int b = id >> 14;
  const float Ae = -expf(A_log[n]) * 1.44269504088896f;
  const size_t hstride = (size_t)NS * HDIM;
  float* hp = hbuf + ((size_t)b * NCHUNK * NS + n) * HDIM + h;
  const float* dp = dts + (size_t)b * NCHUNK * HDIM + h;
  float hs = 0.f;
  float nh = hp[0];
  float nd = dp[0];
  for (int c = 1; c < NCHUNK; ++c) {
    const float curh = nh, curd = nd;
    if (c < NCHUNK - 1) {                    // prefetch slot c (consumed at c+1)
      nh = hp[(size_t)c * hstride];
      nd = dp[(size_t)c * HDIM];
    }
    hs = fmaf(exp2f(Ae * curd), hs, curh);
    hp[(size_t)(c - 1) * hstride] = hs;      // h_start[c] -> slot c-1
  }
}

// ---------------- launcher ----------------
extern "C" void kernel_launch(void* const* d_in, const int* in_sizes, int n_in,
                              void* d_out, int out_size, void* d_ws, size_t ws_size,
                              hipStream_t stream) {
  (void)in_sizes; (void)n_in; (void)out_size; (void)ws_size;
  const float* x     = (const float*)d_in[0];
  const float* Wx    = (const float*)d_in[1];
  const float* A_log = (const float*)d_in[2];
  const float* Dv    = (const float*)d_in[3];
  const float* Wout  = (const float*)d_in[4];
  float* out = (float*)d_out;

  char* ws = (char*)d_ws;
  u16*   x_bf  = (u16*)(ws);                       // 16,777,216 B (read by scans too)
  u16*   wx_bf = (u16*)(ws + 16777216);            //  2,359,296 B (alias: dts after gemm1)
  u16*   wo_bf = (u16*)(ws + 19136512);            //  2,097,152 B
  u16*   dlth  = (u16*)(ws + 21233664);            // 16,777,216 B (fp16 delta)
  float* hbuf  = (float*)(ws + 38010880);          // 16,777,216 B
  float* Bm    = (float*)(ws + 54788096);          //    524,288 B
  float* Cm    = (float*)(ws + 55312384);          //    524,288 B
  u16*   y_bf  = (u16*)(ws + 55836672);            // 16,777,216 B -> end 72,613,888
  float* dts   = (float*)wx_bf;                    // 1 MB needed, wx dead after gemm1

  cvt_all_kernel<<<5184, 256, 0, stream>>>(x, Wx, Wout, x_bf, wx_bf, wo_bf);

  dim3 g1(BL / 64, NXPAD / 128);  // 128 x 9 = 1152 blocks (4.5/CU)
  gemm_bt<1><<<g1, 256, 0, stream>>>(x_bf, wx_bf, nullptr, Bm, Cm, dlth, NXPAD);

  dim3 gs(NBATCH * NCHUNK, HDIM / 256);  // 256 x 4 blocks
  scan_phase<1><<<gs, 256, 0, stream>>>(dlth, x_bf, Bm, Cm, A_log, Dv, hbuf, dts, nullptr);
  scan_combine<<<256, 256, 0, stream>>>(hbuf, dts, A_log);
  scan_phase<3><<<gs, 256, 0, stream>>>(dlth, x_bf, Bm, Cm, A_log, Dv, hbuf, dts, y_bf);

  dim3 g3(BL / 64, HDIM / 128);   // 128 x 8 = 1024 blocks (4/CU)
  gemm_bt<0><<<g3, 256, 0, stream>>>(y_bf, wo_bf, out, nullptr, nullptr, nullptr, HDIM);
}

// Round 8
// 270.152 us; speedup vs baseline: 1.3014x; 1.1720x over previous
//
#include <hip/hip_runtime.h>

#define HDIM 1024
#define LSEQ 2048
#define NBATCH 4
#define NS 16
#define BL (NBATCH * LSEQ)   // 8192 rows
#define KDIM 1024
#define NX 1056              // 2*NS + HDIM
#define NXPAD 1152           // padded to 9*128
#define NCHUNK 64            // L chunks for the 3-phase scan
#define CLEN 32              // LSEQ / NCHUNK

typedef unsigned short u16;
typedef short short8 __attribute__((ext_vector_type(8)));
typedef float f32x4 __attribute__((ext_vector_type(4)));
typedef u16 u16x8 __attribute__((ext_vector_type(8)));

__device__ __forceinline__ u16 f2bf(float f) {
  union { float f; unsigned u; } v; v.f = f;
  unsigned r = v.u + 0x7fffu + ((v.u >> 16) & 1u);   // round-to-nearest-even
  return (u16)(r >> 16);
}
__device__ __forceinline__ float bf2f(u16 b) {
  union { unsigned u; float f; } v; v.u = ((unsigned)b) << 16; return v.f;
}
__device__ __forceinline__ u16 f2h(float f) {          // fp32 -> fp16 (e5m10)
  union { _Float16 h; u16 u; } v; v.h = (_Float16)f; return v.u;
}
__device__ __forceinline__ float h2f(u16 h) {
  union { u16 u; _Float16 h; } v; v.u = h; return (float)v.h;
}

// async global->LDS, 16B per lane; LDS dest = wave-uniform base + lane*16
__device__ __forceinline__ void ld16(const void* g, void* l) {
  __builtin_amdgcn_global_load_lds(
      (const __attribute__((address_space(1))) unsigned int*)g,
      (__attribute__((address_space(3))) unsigned int*)l, 16, 0, 0);
}

// ---------------- fused fp32 -> bf16 conversion (x, Wx->padded, Wout) ------
__global__ __launch_bounds__(256) void cvt_all_kernel(const float* __restrict__ x,
                                                      const float* __restrict__ Wx,
                                                      const float* __restrict__ Wout,
                                                      u16* __restrict__ x_bf,
                                                      u16* __restrict__ wx_bf,
                                                      u16* __restrict__ wo_bf) {
  const int blk = blockIdx.x;
  const float* in;
  u16* out;
  int i;
  bool zero = false;
  if (blk < 4096) {
    i = (blk * 256 + threadIdx.x) * 8;
    in = x; out = x_bf;
  } else if (blk < 4672) {
    i = ((blk - 4096) * 256 + threadIdx.x) * 8;
    in = Wx; out = wx_bf;
    zero = (i >> 10) >= NX;                 // pad rows 1056..1151
  } else {
    i = ((blk - 4672) * 256 + threadIdx.x) * 8;
    in = Wout; out = wo_bf;
  }
  u16x8 r;
  if (!zero) {
    float4 a = *(const float4*)(in + i);
    float4 b = *(const float4*)(in + i + 4);
    r[0] = f2bf(a.x); r[1] = f2bf(a.y); r[2] = f2bf(a.z); r[3] = f2bf(a.w);
    r[4] = f2bf(b.x); r[5] = f2bf(b.y); r[6] = f2bf(b.z); r[7] = f2bf(b.w);
  } else {
#pragma unroll
    for (int t = 0; t < 8; ++t) r[t] = 0;
  }
  *(u16x8*)(out + i) = r;
}

// ---------------- bf16 GEMM:  C(MxN) = A(MxK) * B(NxK)^T ----------------
// r5/r7 config (best measured: ~68 µs): 64x128 tile, BK=64, 4 waves in N,
// 24 KB LDS, 2-barrier K-loop, hoisted staging addresses.
template <int EPI>
__global__ __launch_bounds__(256) void gemm_bt(const u16* __restrict__ A,
                                               const u16* __restrict__ B,
                                               float* __restrict__ C,
                                               float* __restrict__ Bmo,
                                               float* __restrict__ Cmo,
                                               u16* __restrict__ Dlo,
                                               int N) {
  __shared__ __align__(16) u16 S[24 * 512];   // 24 KB
  const int tid = threadIdx.x, lane = tid & 63, w = tid >> 6;
  const int m0 = blockIdx.x * 64, n0 = blockIdx.y * 128;
  const int lr = lane & 15, lq = lane >> 4;
  f32x4 acc[4][2] = {};

  const u16* gp0; const u16* gp1; const u16* gp2;
  const u16* gp3; const u16* gp4; const u16* gp5;
  u16 *lp0, *lp1, *lp2, *lp3, *lp4, *lp5;
  {
    const u16* gp[6]; u16* lp[6];
#pragma unroll
    for (int c = 0; c < 6; ++c) {
      const int ca = w * 6 + c;                     // chunk id 0..23
      if (ca < 8) {                                 // A: 64 rows x 64 k
        const int arow = ((ca >> 1) << 4) + lr;
        const int acol = ((ca & 1) << 5) + (lq << 3);
        gp[c] = A + (size_t)(m0 + arow) * KDIM + acol;
      } else {                                      // B: 128 rows x 64 k
        const int cb = ca - 8;
        const int brow = ((cb >> 1) << 4) + lr;
        const int bcol = ((cb & 1) << 5) + (lq << 3);
        gp[c] = B + (size_t)(n0 + brow) * KDIM + bcol;
      }
      lp[c] = (u16*)(S + ca * 512);
    }
    gp0 = gp[0]; gp1 = gp[1]; gp2 = gp[2]; gp3 = gp[3]; gp4 = gp[4]; gp5 = gp[5];
    lp0 = lp[0]; lp1 = lp[1]; lp2 = lp[2]; lp3 = lp[3]; lp4 = lp[4]; lp5 = lp[5];
  }

  for (int kt = 0; kt < KDIM / 64; ++kt) {
    __syncthreads();
    ld16(gp0, lp0); ld16(gp1, lp1); ld16(gp2, lp2);
    ld16(gp3, lp3); ld16(gp4, lp4); ld16(gp5, lp5);
    gp0 += 64; gp1 += 64; gp2 += 64; gp3 += 64; gp4 += 64; gp5 += 64;
    __syncthreads();
#pragma unroll
    for (int kh = 0; kh < 2; ++kh) {
      short8 af[4], bfr[2];
#pragma unroll
      for (int f = 0; f < 4; ++f)
        af[f] = *(const short8*)(S + (f * 2 + kh) * 512 + lane * 8);
#pragma unroll
      for (int j = 0; j < 2; ++j)
        bfr[j] = *(const short8*)(S + (8 + (w * 2 + j) * 2 + kh) * 512 + lane * 8);
#pragma unroll
      for (int i = 0; i < 4; ++i)
#pragma unroll
        for (int j = 0; j < 2; ++j)
          acc[i][j] = __builtin_amdgcn_mfma_f32_16x16x32_bf16(af[i], bfr[j], acc[i][j], 0, 0, 0);
    }
  }

#pragma unroll
  for (int i = 0; i < 4; ++i) {
    const int gr0 = m0 + i * 16 + lq * 4;
#pragma unroll
    for (int j = 0; j < 2; ++j) {
      const int gc = n0 + w * 32 + j * 16 + lr;
      if (EPI == 0) {
        float* p = C + (size_t)gr0 * N + gc;
#pragma unroll
        for (int r = 0; r < 4; ++r) p[(size_t)r * N] = acc[i][j][r];
      } else {
        const int nt = gc >> 4;  // 16-col tile index
        if (nt == 0) {
#pragma unroll
          for (int r = 0; r < 4; ++r) Bmo[(gr0 + r) * NS + lr] = acc[i][j][r];
        } else if (nt == 1) {
#pragma unroll
          for (int r = 0; r < 4; ++r) Cmo[(gr0 + r) * NS + lr] = acc[i][j][r];
        } else if (nt < 66) {  // cols 32..1055 -> delta 0..1023, fp16
#pragma unroll
          for (int r = 0; r < 4; ++r) {
            float v = acc[i][j][r];
            float sp = fmaxf(v, 0.f) + __logf(1.f + __expf(-fabsf(v)));
            Dlo[(size_t)(gr0 + r) * HDIM + (gc - 2 * NS)] = f2h(sp);
          }
        }
      }
    }
  }
}

// ---------------- chunked selective scan, 3 phases ----------------
// ROUND-8: barrier-free step loop. dt/x are loaded DIRECTLY to registers
// (fixed h per thread -> coalesced across threads, 8-step batches, two
// batches in flight = 32 loads outstanding, fine-grained vmcnt waits).
// r2-r7's LDS staging forced a vmcnt(0)+lgkmcnt(0) drain at 4 barriers per
// block — the same structural stall as the GEMM K-loop; scans stayed ~60 µs
// with all pipes <20% (latency-bound, confirmed by r7's traffic halving
// being a no-op). Bm/Cm still staged to LDS once at block start (broadcast
// reads). exp2 via raw v_exp_f32 (__builtin_amdgcn_exp2f): args in
// [-126,0]; flush-to-zero = correct decay. OCML exp2f's guarded path was
// ~5x the trans cost.
template <int PHASE>
__global__ __launch_bounds__(256) void scan_phase(
    const u16* __restrict__ dlth, const u16* __restrict__ xb,
    const float* __restrict__ Bm, const float* __restrict__ Cm,
    const float* __restrict__ A_log, const float* __restrict__ Dvec,
    float* __restrict__ hbuf,      // [b][chunk][n][h]
    float* __restrict__ dts_out,   // [b][chunk][h]
    u16* __restrict__ yout) {
  __shared__ __align__(16) float sbt[CLEN][16];     // 2 KB
  __shared__ __align__(16) float sct[CLEN][16];     // 2 KB
  const int tid = threadIdx.x, lane = tid & 63, w = tid >> 6;
  const int b = blockIdx.x >> 6, c = blockIdx.x & 63;
  const int h0 = blockIdx.y << 8, h = h0 + tid;
  const size_t l0 = (size_t)b * LSEQ + (size_t)c * CLEN;

  if (w == 0) {
#pragma unroll
    for (int i = 0; i < 2; ++i)
      ld16(Bm + l0 * NS + i * 256 + lane * 4, (void*)(&sbt[0][0] + i * 256));
  } else if (w == 1 && PHASE == 3) {
#pragma unroll
    for (int i = 0; i < 2; ++i)
      ld16(Cm + l0 * NS + i * 256 + lane * 4, (void*)(&sct[0][0] + i * 256));
  }

  const u16* pd = dlth + l0 * HDIM + h;
  const u16* px = xb + l0 * HDIM + h;

  float Ae[16], hs[16];
#pragma unroll
  for (int n = 0; n < 16; ++n) Ae[n] = -expf(A_log[n]) * 1.44269504088896f;
  if (PHASE == 3 && c > 0) {
    const float* hp = hbuf + ((size_t)b * NCHUNK + (c - 1)) * NS * HDIM + h;
#pragma unroll
    for (int n = 0; n < 16; ++n) hs[n] = hp[(size_t)n * HDIM];
  } else {
#pragma unroll
    for (int n = 0; n < 16; ++n) hs[n] = 0.f;
  }
  const float Dh = (PHASE == 3) ? Dvec[h] : 0.f;
  float dts = 0.f;

  u16 d0[8], x0[8], d1[8], x1[8];
  auto loadb = [&](int ks, u16* dd, u16* xx) {
#pragma unroll
    for (int j = 0; j < 8; ++j) {
      dd[j] = pd[(size_t)(ks * 8 + j) * HDIM];
      xx[j] = px[(size_t)(ks * 8 + j) * HDIM];
    }
  };
  auto compute = [&](int ks, const u16* dd, const u16* xx) {
#pragma unroll
    for (int s = 0; s < 8; ++s) {
      const int l = ks * 8 + s;
      const float dt = h2f(dd[s]);
      const float xt = bf2f(xx[s]);
      const float dxt = dt * xt;
      if (PHASE == 1) dts += dt;
      float y = Dh * xt;
      const f32x4* btp = (const f32x4*)&sbt[l][0];
      const f32x4* ctp = (const f32x4*)&sct[l][0];
#pragma unroll
      for (int q = 0; q < 4; ++q) {
        const f32x4 b4 = btp[q];               // broadcast read (same addr)
        f32x4 c4;
        if (PHASE == 3) c4 = ctp[q];
#pragma unroll
        for (int r = 0; r < 4; ++r) {
          const int n = q * 4 + r;
          const float dA = __builtin_amdgcn_exp2f(dt * Ae[n]);
          hs[n] = fmaf(dA, hs[n], b4[r] * dxt);
          if (PHASE == 3) y = fmaf(hs[n], c4[r], y);
        }
      }
      if (PHASE == 3) yout[(l0 + l) * HDIM + h] = f2bf(y);
    }
  };

  loadb(0, d0, x0);
  loadb(1, d1, x1);
  __syncthreads();                  // sbt/sct ready (only barrier in kernel)
  compute(0, d0, x0); loadb(2, d0, x0);
  compute(1, d1, x1); loadb(3, d1, x1);
  compute(2, d0, x0);
  compute(3, d1, x1);

  if (PHASE == 1) {
    float* hp = hbuf + ((size_t)b * NCHUNK + c) * NS * HDIM + h;
#pragma unroll
    for (int n = 0; n < 16; ++n) hp[(size_t)n * HDIM] = hs[n];
    dts_out[((size_t)b * NCHUNK + c) * HDIM + h] = dts;
  }
}

// PHASE 2: sequential prefix over chunks, in place (slot-shifted).
__global__ __launch_bounds__(256) void scan_combine(
    float* __restrict__ hbuf, const float* __restrict__ dts,
    const float* __restrict__ A_log) {
  const int id = blockIdx.x * 256 + threadIdx.x;   // 65536 = B*NS*H
  const int h = id & (HDIM - 1);
  const int n = (id >> 10) & (NS - 1);
  const int b = id >> 14;
  const float Ae = -expf(A_log[n]) * 1.44269504088896f;
  const size_t hstride = (size_t)NS * HDIM;
  float* hp = hbuf + ((size_t)b * NCHUNK * NS + n) * HDIM + h;
  const float* dp = dts + (size_t)b * NCHUNK * HDIM + h;
  float hs = 0.f;
  float nh = hp[0];
  float nd = dp[0];
  for (int c = 1; c < NCHUNK; ++c) {
    const float curh = nh, curd = nd;
    if (c < NCHUNK - 1) {                    // prefetch slot c (consumed at c+1)
      nh = hp[(size_t)c * hstride];
      nd = dp[(size_t)c * HDIM];
    }
    hs = fmaf(__builtin_amdgcn_exp2f(Ae * curd), hs, curh);
    hp[(size_t)(c - 1) * hstride] = hs;      // h_start[c] -> slot c-1
  }
}

// ---------------- launcher ----------------
extern "C" void kernel_launch(void* const* d_in, const int* in_sizes, int n_in,
                              void* d_out, int out_size, void* d_ws, size_t ws_size,
                              hipStream_t stream) {
  (void)in_sizes; (void)n_in; (void)out_size; (void)ws_size;
  const float* x     = (const float*)d_in[0];
  const float* Wx    = (const float*)d_in[1];
  const float* A_log = (const float*)d_in[2];
  const float* Dv    = (const float*)d_in[3];
  const float* Wout  = (const float*)d_in[4];
  float* out = (float*)d_out;

  char* ws = (char*)d_ws;
  u16*   x_bf  = (u16*)(ws);                       // 16,777,216 B (read by scans too)
  u16*   wx_bf = (u16*)(ws + 16777216);            //  2,359,296 B (alias: dts after gemm1)
  u16*   wo_bf = (u16*)(ws + 19136512);            //  2,097,152 B
  u16*   dlth  = (u16*)(ws + 21233664);            // 16,777,216 B (fp16 delta)
  float* hbuf  = (float*)(ws + 38010880);          // 16,777,216 B
  float* Bm    = (float*)(ws + 54788096);          //    524,288 B
  float* Cm    = (float*)(ws + 55312384);          //    524,288 B
  u16*   y_bf  = (u16*)(ws + 55836672);            // 16,777,216 B -> end 72,613,888
  float* dts   = (float*)wx_bf;                    // 1 MB needed, wx dead after gemm1

  cvt_all_kernel<<<5184, 256, 0, stream>>>(x, Wx, Wout, x_bf, wx_bf, wo_bf);

  dim3 g1(BL / 64, NXPAD / 128);  // 128 x 9 = 1152 blocks (4.5/CU)
  gemm_bt<1><<<g1, 256, 0, stream>>>(x_bf, wx_bf, nullptr, Bm, Cm, dlth, NXPAD);

  dim3 gs(NBATCH * NCHUNK, HDIM / 256);  // 256 x 4 blocks
  scan_phase<1><<<gs, 256, 0, stream>>>(dlth, x_bf, Bm, Cm, A_log, Dv, hbuf, dts, nullptr);
  scan_combine<<<256, 256, 0, stream>>>(hbuf, dts, A_log);
  scan_phase<3><<<gs, 256, 0, stream>>>(dlth, x_bf, Bm, Cm, A_log, Dv, hbuf, dts, y_bf);

  dim3 g3(BL / 64, HDIM / 128);   // 128 x 8 = 1024 blocks (4/CU)
  gemm_bt<0><<<g3, 256, 0, stream>>>(y_bf, wo_bf, out, nullptr, nullptr, nullptr, HDIM);
}